// Round 6
// baseline (351.391 us; speedup 1.0000x reference)
//
#include <hip/hip_runtime.h>

#define NN 100000
#define NE 3200000
#define DIN 128
#define HD 32
#define MID 16
#define OUTD 8
#define LN_EPS 1e-5f

#define BINSHIFT 8                 // 256 nodes per bin
#define NB 391                     // ceil(NN / 256)
#define CAP 10240                  // bin capacity (mean 8192)
#define EPB 2048                   // edges per pass-A block (1563 blocks)
#define AITER (EPB / 256)          // 8

// ---------------- bf16 helpers ----------------

__device__ __forceinline__ float bf2f(unsigned short u) {
    union { unsigned int i; float f; } c;
    c.i = ((unsigned int)u) << 16;
    return c.f;
}
__device__ __forceinline__ unsigned short f2bf(float f) {
    union { float f; unsigned int i; } c;
    c.f = f;
    unsigned int r = c.i + 0x7FFFu + ((c.i >> 16) & 1u);  // RNE
    return (unsigned short)(r >> 16);
}
__device__ __forceinline__ unsigned int pack2(float a, float b) {
    return (unsigned int)f2bf(a) | ((unsigned int)f2bf(b) << 16);
}

// ---------------- binned CSR build ----------------

__global__ void k_zero_bins(int* __restrict__ g_bincur) {
    int i = blockIdx.x * blockDim.x + threadIdx.x;
    if (i < NB) g_bincur[i] = 0;
}

__global__ void k_binA(const int* __restrict__ src, const int* __restrict__ dst,
                       int* __restrict__ g_bincur, unsigned int* __restrict__ staged) {
    __shared__ int cnt[NB];
    __shared__ int base[NB];
    for (int t = threadIdx.x; t < NB; t += 256) cnt[t] = 0;
    __syncthreads();
    int e0 = blockIdx.x * EPB;
#pragma unroll
    for (int i = 0; i < AITER; ++i) {
        int e = e0 + i * 256 + threadIdx.x;
        if (e < NE) atomicAdd(&cnt[dst[e] >> BINSHIFT], 1);
    }
    __syncthreads();
    for (int t = threadIdx.x; t < NB; t += 256) {
        int c = cnt[t];
        base[t] = c ? atomicAdd(&g_bincur[t], c) : 0;
        cnt[t] = 0;  // reuse as intra-block cursor
    }
    __syncthreads();
#pragma unroll
    for (int i = 0; i < AITER; ++i) {
        int e = e0 + i * 256 + threadIdx.x;
        if (e < NE) {
            int d = dst[e];
            int b = d >> BINSHIFT;
            int k = base[b] + atomicAdd(&cnt[b], 1);
            if (k < CAP)
                staged[(size_t)b * CAP + k] =
                    ((unsigned int)(d & 255) << 24) | (unsigned int)src[e];
        }
    }
}

__global__ void k_binscan(const int* __restrict__ g_bincur, int* __restrict__ g_binexcl,
                          int* __restrict__ row_ptr) {
    __shared__ int s[512];
    int v = (threadIdx.x < NB) ? min(g_bincur[threadIdx.x], CAP) : 0;
    s[threadIdx.x] = v;
    __syncthreads();
#pragma unroll
    for (int off = 1; off < 512; off <<= 1) {
        int t = (threadIdx.x >= off) ? s[threadIdx.x - off] : 0;
        __syncthreads();
        s[threadIdx.x] += t;
        __syncthreads();
    }
    if (threadIdx.x < NB) g_binexcl[threadIdx.x] = s[threadIdx.x] - v;
    if (threadIdx.x == NB - 1) row_ptr[NN] = s[threadIdx.x];
}

__global__ void k_binC(const int* __restrict__ g_bincur, const int* __restrict__ g_binexcl,
                       const unsigned int* __restrict__ staged,
                       int* __restrict__ row_ptr, float* __restrict__ dis,
                       int* __restrict__ csr_src) {
    __shared__ int cnt[256];
    __shared__ int scn[256];
    int b = blockIdx.x;
    int tot = min(g_bincur[b], CAP);
    cnt[threadIdx.x] = 0;
    __syncthreads();
    const unsigned int* st = staged + (size_t)b * CAP;
    for (int i = threadIdx.x; i < tot; i += 256)
        atomicAdd(&cnt[st[i] >> 24], 1);
    __syncthreads();
    int v = cnt[threadIdx.x];
    scn[threadIdx.x] = v;
    __syncthreads();
#pragma unroll
    for (int off = 1; off < 256; off <<= 1) {
        int t = (threadIdx.x >= off) ? scn[threadIdx.x - off] : 0;
        __syncthreads();
        scn[threadIdx.x] += t;
        __syncthreads();
    }
    int excl = scn[threadIdx.x] - v;
    int gbase = g_binexcl[b];
    int node = (b << BINSHIFT) + threadIdx.x;
    if (node < NN) {
        row_ptr[node] = gbase + excl;
        dis[node] = rsqrtf((float)(v + 1));  // +1 self-loop
    }
    cnt[threadIdx.x] = excl;  // reuse as scatter cursor
    __syncthreads();
    for (int i = threadIdx.x; i < tot; i += 256) {
        unsigned int p = st[i];
        int rank = atomicAdd(&cnt[p >> 24], 1);
        csr_src[gbase + rank] = (int)(p & 0xFFFFFFu);
    }
}

// ---------------- GEMM: thread = node, W via uniform (SGPR) loads ----------------
// hs[n][j] = (x[n] @ W)[j] * dis[n]  packed bf16

template <int K>
__global__ void k_gemm(const float* __restrict__ x, const float* __restrict__ W,
                       const float* __restrict__ dis, unsigned short* __restrict__ hs) {
    int n = blockIdx.x * blockDim.x + threadIdx.x;
    if (n >= NN) return;
    float d = dis[n];
    const float* xr = x + (size_t)n * K;
    float acc[HD];
#pragma unroll
    for (int j = 0; j < HD; ++j) acc[j] = 0.f;
    for (int k0 = 0; k0 < K; k0 += 4) {
        float4 xv = *reinterpret_cast<const float4*>(xr + k0);
#pragma unroll
        for (int kk = 0; kk < 4; ++kk) {
            float xk = kk == 0 ? xv.x : kk == 1 ? xv.y : kk == 2 ? xv.z : xv.w;
#pragma unroll
            for (int j = 0; j < HD; ++j)
                acc[j] = fmaf(xk, W[(k0 + kk) * HD + j], acc[j]);  // W uniform -> s_load
        }
    }
    uint4* hv = reinterpret_cast<uint4*>(hs + (size_t)n * HD);
#pragma unroll
    for (int q = 0; q < 4; ++q) {
        uint4 p;
        p.x = pack2(acc[q * 8 + 0] * d, acc[q * 8 + 1] * d);
        p.y = pack2(acc[q * 8 + 2] * d, acc[q * 8 + 3] * d);
        p.z = pack2(acc[q * 8 + 4] * d, acc[q * 8 + 5] * d);
        p.w = pack2(acc[q * 8 + 6] * d, acc[q * 8 + 7] * d);
        hv[q] = p;
    }
}

// ---------------- gather: out = dis[n]*(hs[n] + sum hs[src]) + epilogue ----------------

#define H8(a) \
    { \
        float v0 = bf2f(h[(size_t)(a).x * HD + c]); \
        float v1 = bf2f(h[(size_t)(a).y * HD + c]); \
        float v2 = bf2f(h[(size_t)(a).z * HD + c]); \
        float v3 = bf2f(h[(size_t)(a).w * HD + c]); \
        acc += (v0 + v1) + (v2 + v3); \
    }

template <int DO_LN>
__global__ void k_gather(const int* __restrict__ row_ptr, const int* __restrict__ csr_src,
                         const float* __restrict__ dis,
                         const unsigned short* __restrict__ h,
                         const float* __restrict__ bias,
                         const float* __restrict__ g, const float* __restrict__ bln,
                         float* __restrict__ out) {
    int idx = blockIdx.x * blockDim.x + threadIdx.x;
    int n = idx >> 5, c = idx & 31;
    if (n >= NN) return;
    float acc = bf2f(h[(size_t)n * HD + c]);  // self-loop (pre-scaled by dis[n])
    int e = row_ptr[n], end = row_ptr[n + 1];
    // peel to 16B alignment of csr_src
    while (e < end && (e & 3)) {
        acc += bf2f(h[(size_t)csr_src[e] * HD + c]);
        ++e;
    }
    for (; e + 15 < end; e += 16) {
        int4 a0 = *reinterpret_cast<const int4*>(csr_src + e);
        int4 a1 = *reinterpret_cast<const int4*>(csr_src + e + 4);
        int4 a2 = *reinterpret_cast<const int4*>(csr_src + e + 8);
        int4 a3 = *reinterpret_cast<const int4*>(csr_src + e + 12);
        float v0 = bf2f(h[(size_t)a0.x * HD + c]);
        float v1 = bf2f(h[(size_t)a0.y * HD + c]);
        float v2 = bf2f(h[(size_t)a0.z * HD + c]);
        float v3 = bf2f(h[(size_t)a0.w * HD + c]);
        float v4 = bf2f(h[(size_t)a1.x * HD + c]);
        float v5 = bf2f(h[(size_t)a1.y * HD + c]);
        float v6 = bf2f(h[(size_t)a1.z * HD + c]);
        float v7 = bf2f(h[(size_t)a1.w * HD + c]);
        float v8 = bf2f(h[(size_t)a2.x * HD + c]);
        float v9 = bf2f(h[(size_t)a2.y * HD + c]);
        float va = bf2f(h[(size_t)a2.z * HD + c]);
        float vb = bf2f(h[(size_t)a2.w * HD + c]);
        float vc = bf2f(h[(size_t)a3.x * HD + c]);
        float vd = bf2f(h[(size_t)a3.y * HD + c]);
        float ve = bf2f(h[(size_t)a3.z * HD + c]);
        float vf = bf2f(h[(size_t)a3.w * HD + c]);
        acc += (((v0 + v1) + (v2 + v3)) + ((v4 + v5) + (v6 + v7))) +
               (((v8 + v9) + (va + vb)) + ((vc + vd) + (ve + vf)));
    }
    if (e + 7 < end) {
        int4 a0 = *reinterpret_cast<const int4*>(csr_src + e);
        int4 a1 = *reinterpret_cast<const int4*>(csr_src + e + 4);
        H8(a0);
        H8(a1);
        e += 8;
    }
    if (e + 3 < end) {
        int4 a0 = *reinterpret_cast<const int4*>(csr_src + e);
        H8(a0);
        e += 4;
    }
    for (; e < end; ++e)
        acc += bf2f(h[(size_t)csr_src[e] * HD + c]);

    float v = fmaxf(acc * dis[n] + bias[c], 0.f);
    if (DO_LN) {
        float s = v, s2 = v * v;
#pragma unroll
        for (int m = 16; m >= 1; m >>= 1) {
            s += __shfl_xor(s, m, 32);
            s2 += __shfl_xor(s2, m, 32);
        }
        float mean = s * (1.f / 32.f);
        float var = s2 * (1.f / 32.f) - mean * mean;
        v = (v - mean) * rsqrtf(var + LN_EPS) * g[c] + bln[c];
    }
    out[(size_t)n * HD + c] = v;
}

// ---------------- final: MLP head + log_softmax ----------------

__global__ void k_final(const float* __restrict__ hin,
                        const float* __restrict__ w1, const float* __restrict__ mb1,
                        const float* __restrict__ w2, const float* __restrict__ mb2,
                        float* __restrict__ out) {
    __shared__ float sw1[HD * MID], sw2[MID * OUTD], sb1[MID], sb2[OUTD];
    for (int t = threadIdx.x; t < HD * MID; t += blockDim.x) sw1[t] = w1[t];
    for (int t = threadIdx.x; t < MID * OUTD; t += blockDim.x) sw2[t] = w2[t];
    if (threadIdx.x < MID) sb1[threadIdx.x] = mb1[threadIdx.x];
    if (threadIdx.x < OUTD) sb2[threadIdx.x] = mb2[threadIdx.x];
    __syncthreads();
    int n = blockIdx.x * blockDim.x + threadIdx.x;
    if (n >= NN) return;
    float h[HD];
    const float* ar = hin + (size_t)n * HD;
#pragma unroll
    for (int k = 0; k < HD; ++k) h[k] = ar[k];
    float t[MID];
#pragma unroll
    for (int j = 0; j < MID; ++j) {
        float a = sb1[j];
#pragma unroll
        for (int k = 0; k < HD; ++k) a += h[k] * sw1[k * MID + j];
        t[j] = fmaxf(a, 0.f);
    }
    float o[OUTD];
#pragma unroll
    for (int j = 0; j < OUTD; ++j) {
        float a = sb2[j];
#pragma unroll
        for (int k = 0; k < MID; ++k) a += t[k] * sw2[k * OUTD + j];
        o[j] = a;
    }
    float mx = o[0];
#pragma unroll
    for (int j = 1; j < OUTD; ++j) mx = fmaxf(mx, o[j]);
    float se = 0.f;
#pragma unroll
    for (int j = 0; j < OUTD; ++j) se += __expf(o[j] - mx);
    float lse = __logf(se) + mx;
    float* orow = out + (size_t)n * OUTD;
#pragma unroll
    for (int j = 0; j < OUTD; ++j) orow[j] = o[j] - lse;
}

// ---------------- launch ----------------

extern "C" void kernel_launch(void* const* d_in, const int* in_sizes, int n_in,
                              void* d_out, int out_size, void* d_ws, size_t ws_size,
                              hipStream_t stream) {
    const float* x     = (const float*)d_in[0];
    const int*   ei    = (const int*)d_in[1];
    const float* W0    = (const float*)d_in[2];
    const float* b0    = (const float*)d_in[3];
    const float* W1    = (const float*)d_in[4];
    const float* b1    = (const float*)d_in[5];
    const float* W2    = (const float*)d_in[6];
    const float* b2    = (const float*)d_in[7];
    const float* ln0_g = (const float*)d_in[8];
    const float* ln0_b = (const float*)d_in[9];
    const float* ln1_g = (const float*)d_in[10];
    const float* ln1_b = (const float*)d_in[11];
    const float* mp_w1 = (const float*)d_in[12];
    const float* mp_b1 = (const float*)d_in[13];
    const float* mp_w2 = (const float*)d_in[14];
    const float* mp_b2 = (const float*)d_in[15];
    float* out = (float*)d_out;

    const int* src = ei;        // edge_index[0]
    const int* dst = ei + NE;   // edge_index[1]

    char* w = (char*)d_ws;
    auto align256 = [](size_t v) { return (v + 255) & ~(size_t)255; };
    int* g_bincur  = (int*)w;   w += align256((size_t)NB * 4);
    int* g_binexcl = (int*)w;   w += align256((size_t)NB * 4);
    int* row_ptr   = (int*)w;   w += align256((size_t)(NN + 1) * 4);
    float* dis     = (float*)w; w += align256((size_t)NN * 4);
    char* uni = w;              // union region (staging vs activations)
    unsigned int* staged = (unsigned int*)uni;                    // NB*CAP*4 = 16.0 MB
    unsigned short* bufB = (unsigned short*)uni;                  // bf16 hs, 6.4 MB
    float* bufA = (float*)(uni + align256((size_t)NN * HD * 2));  // f32 acts, 12.8 MB
    size_t uni_sz = align256((size_t)NB * CAP * 4);
    size_t uni_sz2 = align256((size_t)NN * HD * 2) + align256((size_t)NN * HD * 4);
    w = uni + (uni_sz > uni_sz2 ? uni_sz : uni_sz2);
    int* csr_src = (int*)w;

    const int BS = 256;
    int gN   = (NN + BS - 1) / BS;          // 391
    int gA   = (NE + EPB - 1) / EPB;        // 1563
    int gN32 = (NN * HD + BS - 1) / BS;

    // CSR build (binned counting sort)
    k_zero_bins<<<1, 512, 0, stream>>>(g_bincur);
    k_binA<<<gA, BS, 0, stream>>>(src, dst, g_bincur, staged);
    k_binscan<<<1, 512, 0, stream>>>(g_bincur, g_binexcl, row_ptr);
    k_binC<<<NB, BS, 0, stream>>>(g_bincur, g_binexcl, staged, row_ptr, dis, csr_src);

    // layer 0
    k_gemm<DIN><<<gN, BS, 0, stream>>>(x, W0, dis, bufB);
    k_gather<1><<<gN32, BS, 0, stream>>>(row_ptr, csr_src, dis, bufB, b0,
                                         ln0_g, ln0_b, bufA);
    // layer 1
    k_gemm<HD><<<gN, BS, 0, stream>>>(bufA, W1, dis, bufB);
    k_gather<1><<<gN32, BS, 0, stream>>>(row_ptr, csr_src, dis, bufB, b1,
                                         ln1_g, ln1_b, bufA);
    // layer 2 (no LN)
    k_gemm<HD><<<gN, BS, 0, stream>>>(bufA, W2, dis, bufB);
    k_gather<0><<<gN32, BS, 0, stream>>>(row_ptr, csr_src, dis, bufB, b2,
                                         nullptr, nullptr, bufA);

    // head
    k_final<<<gN, BS, 0, stream>>>(bufA, mp_w1, mp_b1, mp_w2, mp_b2, out);
}

// Round 7
// 299.670 us; speedup vs baseline: 1.1726x; 1.1726x over previous
//
#include <hip/hip_runtime.h>

#define NN 100000
#define NE 3200000
#define DIN 128
#define HD 32
#define MID 16
#define OUTD 8
#define LN_EPS 1e-5f

#define BINSHIFT 8                 // 256 nodes per bin
#define NB 391                     // ceil(NN / 256)
#define CAP 10240                  // bin capacity (mean 8192)
#define EPB 8192                   // edges per pass-A block (391 blocks, 21-edge runs)
#define ABS 1024                   // pass-A block size (16 waves/block)
#define AITER (EPB / ABS)          // 8

// ---------------- bf16 helpers ----------------

__device__ __forceinline__ float bf2f(unsigned short u) {
    union { unsigned int i; float f; } c;
    c.i = ((unsigned int)u) << 16;
    return c.f;
}
__device__ __forceinline__ unsigned short f2bf(float f) {
    union { float f; unsigned int i; } c;
    c.f = f;
    unsigned int r = c.i + 0x7FFFu + ((c.i >> 16) & 1u);  // RNE
    return (unsigned short)(r >> 16);
}
__device__ __forceinline__ unsigned int pack2(float a, float b) {
    return (unsigned int)f2bf(a) | ((unsigned int)f2bf(b) << 16);
}

// ---------------- binned CSR build ----------------

__global__ void k_zero_bins(int* __restrict__ g_bincur) {
    int i = blockIdx.x * blockDim.x + threadIdx.x;
    if (i < NB) g_bincur[i] = 0;
}

__global__ __launch_bounds__(ABS) void k_binA(const int* __restrict__ src,
                                              const int* __restrict__ dst,
                                              int* __restrict__ g_bincur,
                                              unsigned int* __restrict__ staged) {
    __shared__ int cnt[NB];
    __shared__ int base[NB];
    int tid = threadIdx.x;
    for (int t = tid; t < NB; t += ABS) cnt[t] = 0;
    __syncthreads();
    int e0 = blockIdx.x * EPB;
    int dreg[AITER];
#pragma unroll
    for (int i = 0; i < AITER; ++i) {
        int e = e0 + i * ABS + tid;
        dreg[i] = (e < NE) ? dst[e] : -1;
        if (dreg[i] >= 0) atomicAdd(&cnt[dreg[i] >> BINSHIFT], 1);
    }
    __syncthreads();
    for (int t = tid; t < NB; t += ABS) {
        int c = cnt[t];
        base[t] = c ? atomicAdd(&g_bincur[t], c) : 0;
        cnt[t] = 0;  // reuse as intra-block cursor
    }
    __syncthreads();
#pragma unroll
    for (int i = 0; i < AITER; ++i) {
        int e = e0 + i * ABS + tid;
        int d = dreg[i];
        if (d >= 0) {
            int b = d >> BINSHIFT;
            int k = base[b] + atomicAdd(&cnt[b], 1);
            if (k < CAP)
                staged[(size_t)b * CAP + k] =
                    ((unsigned int)(d & 255) << 24) | (unsigned int)src[e];
        }
    }
}

__global__ void k_binscan(const int* __restrict__ g_bincur, int* __restrict__ g_binexcl,
                          int* __restrict__ row_ptr) {
    __shared__ int s[512];
    int v = (threadIdx.x < NB) ? min(g_bincur[threadIdx.x], CAP) : 0;
    s[threadIdx.x] = v;
    __syncthreads();
#pragma unroll
    for (int off = 1; off < 512; off <<= 1) {
        int t = (threadIdx.x >= off) ? s[threadIdx.x - off] : 0;
        __syncthreads();
        s[threadIdx.x] += t;
        __syncthreads();
    }
    if (threadIdx.x < NB) g_binexcl[threadIdx.x] = s[threadIdx.x] - v;
    if (threadIdx.x == NB - 1) row_ptr[NN] = s[threadIdx.x];
}

#define CBS 1024                   // pass-C block size

__global__ __launch_bounds__(CBS) void k_binC(const int* __restrict__ g_bincur,
                                              const int* __restrict__ g_binexcl,
                                              const unsigned int* __restrict__ staged,
                                              int* __restrict__ row_ptr,
                                              float* __restrict__ dis,
                                              int* __restrict__ csr_src) {
    __shared__ int cnt[256];
    __shared__ int scn[256];
    int b = blockIdx.x;
    int tid = threadIdx.x;
    int tot = min(g_bincur[b], CAP);
    if (tid < 256) cnt[tid] = 0;
    __syncthreads();
    const unsigned int* st = staged + (size_t)b * CAP;
    for (int i = tid; i < tot; i += CBS)
        atomicAdd(&cnt[st[i] >> 24], 1);
    __syncthreads();
    int v = 0;
    if (tid < 256) {
        v = cnt[tid];
        scn[tid] = v;
    }
    __syncthreads();
#pragma unroll
    for (int off = 1; off < 256; off <<= 1) {
        int t = (tid < 256 && tid >= off) ? scn[tid - off] : 0;
        __syncthreads();
        if (tid < 256) scn[tid] += t;
        __syncthreads();
    }
    int gbase = g_binexcl[b];
    if (tid < 256) {
        int excl = scn[tid] - v;
        int node = (b << BINSHIFT) + tid;
        if (node < NN) {
            row_ptr[node] = gbase + excl;
            dis[node] = rsqrtf((float)(v + 1));  // +1 self-loop
        }
        cnt[tid] = excl;  // reuse as scatter cursor
    }
    __syncthreads();
    for (int i = tid; i < tot; i += CBS) {
        unsigned int p = st[i];
        int rank = atomicAdd(&cnt[p >> 24], 1);
        csr_src[gbase + rank] = (int)(p & 0xFFFFFFu);
    }
}

// ---------------- GEMM: thread = node, W via uniform (SGPR) loads ----------------
// hs[n][j] = (x[n] @ W)[j] * dis[n]  packed bf16

template <int K>
__global__ void k_gemm(const float* __restrict__ x, const float* __restrict__ W,
                       const float* __restrict__ dis, unsigned short* __restrict__ hs) {
    int n = blockIdx.x * blockDim.x + threadIdx.x;
    if (n >= NN) return;
    float d = dis[n];
    const float* xr = x + (size_t)n * K;
    float acc[HD];
#pragma unroll
    for (int j = 0; j < HD; ++j) acc[j] = 0.f;
    for (int k0 = 0; k0 < K; k0 += 4) {
        float4 xv = *reinterpret_cast<const float4*>(xr + k0);
#pragma unroll
        for (int kk = 0; kk < 4; ++kk) {
            float xk = kk == 0 ? xv.x : kk == 1 ? xv.y : kk == 2 ? xv.z : xv.w;
#pragma unroll
            for (int j = 0; j < HD; ++j)
                acc[j] = fmaf(xk, W[(k0 + kk) * HD + j], acc[j]);  // W uniform -> s_load
        }
    }
    uint4* hv = reinterpret_cast<uint4*>(hs + (size_t)n * HD);
#pragma unroll
    for (int q = 0; q < 4; ++q) {
        uint4 p;
        p.x = pack2(acc[q * 8 + 0] * d, acc[q * 8 + 1] * d);
        p.y = pack2(acc[q * 8 + 2] * d, acc[q * 8 + 3] * d);
        p.z = pack2(acc[q * 8 + 4] * d, acc[q * 8 + 5] * d);
        p.w = pack2(acc[q * 8 + 6] * d, acc[q * 8 + 7] * d);
        hv[q] = p;
    }
}

// ---------------- gather: out = dis[n]*(hs[n] + sum hs[src]) + epilogue ----------------

#define H8(a) \
    { \
        float v0 = bf2f(h[(size_t)(a).x * HD + c]); \
        float v1 = bf2f(h[(size_t)(a).y * HD + c]); \
        float v2 = bf2f(h[(size_t)(a).z * HD + c]); \
        float v3 = bf2f(h[(size_t)(a).w * HD + c]); \
        acc += (v0 + v1) + (v2 + v3); \
    }

template <int DO_LN>
__global__ void k_gather(const int* __restrict__ row_ptr, const int* __restrict__ csr_src,
                         const float* __restrict__ dis,
                         const unsigned short* __restrict__ h,
                         const float* __restrict__ bias,
                         const float* __restrict__ g, const float* __restrict__ bln,
                         float* __restrict__ out) {
    int idx = blockIdx.x * blockDim.x + threadIdx.x;
    int n = idx >> 5, c = idx & 31;
    if (n >= NN) return;
    float acc = bf2f(h[(size_t)n * HD + c]);  // self-loop (pre-scaled by dis[n])
    int e = row_ptr[n], end = row_ptr[n + 1];
    // peel to 16B alignment of csr_src
    while (e < end && (e & 3)) {
        acc += bf2f(h[(size_t)csr_src[e] * HD + c]);
        ++e;
    }
    for (; e + 15 < end; e += 16) {
        int4 a0 = *reinterpret_cast<const int4*>(csr_src + e);
        int4 a1 = *reinterpret_cast<const int4*>(csr_src + e + 4);
        int4 a2 = *reinterpret_cast<const int4*>(csr_src + e + 8);
        int4 a3 = *reinterpret_cast<const int4*>(csr_src + e + 12);
        float v0 = bf2f(h[(size_t)a0.x * HD + c]);
        float v1 = bf2f(h[(size_t)a0.y * HD + c]);
        float v2 = bf2f(h[(size_t)a0.z * HD + c]);
        float v3 = bf2f(h[(size_t)a0.w * HD + c]);
        float v4 = bf2f(h[(size_t)a1.x * HD + c]);
        float v5 = bf2f(h[(size_t)a1.y * HD + c]);
        float v6 = bf2f(h[(size_t)a1.z * HD + c]);
        float v7 = bf2f(h[(size_t)a1.w * HD + c]);
        float v8 = bf2f(h[(size_t)a2.x * HD + c]);
        float v9 = bf2f(h[(size_t)a2.y * HD + c]);
        float va = bf2f(h[(size_t)a2.z * HD + c]);
        float vb = bf2f(h[(size_t)a2.w * HD + c]);
        float vc = bf2f(h[(size_t)a3.x * HD + c]);
        float vd = bf2f(h[(size_t)a3.y * HD + c]);
        float ve = bf2f(h[(size_t)a3.z * HD + c]);
        float vf = bf2f(h[(size_t)a3.w * HD + c]);
        acc += (((v0 + v1) + (v2 + v3)) + ((v4 + v5) + (v6 + v7))) +
               (((v8 + v9) + (va + vb)) + ((vc + vd) + (ve + vf)));
    }
    if (e + 7 < end) {
        int4 a0 = *reinterpret_cast<const int4*>(csr_src + e);
        int4 a1 = *reinterpret_cast<const int4*>(csr_src + e + 4);
        H8(a0);
        H8(a1);
        e += 8;
    }
    if (e + 3 < end) {
        int4 a0 = *reinterpret_cast<const int4*>(csr_src + e);
        H8(a0);
        e += 4;
    }
    for (; e < end; ++e)
        acc += bf2f(h[(size_t)csr_src[e] * HD + c]);

    float v = fmaxf(acc * dis[n] + bias[c], 0.f);
    if (DO_LN) {
        float s = v, s2 = v * v;
#pragma unroll
        for (int m = 16; m >= 1; m >>= 1) {
            s += __shfl_xor(s, m, 32);
            s2 += __shfl_xor(s2, m, 32);
        }
        float mean = s * (1.f / 32.f);
        float var = s2 * (1.f / 32.f) - mean * mean;
        v = (v - mean) * rsqrtf(var + LN_EPS) * g[c] + bln[c];
    }
    out[(size_t)n * HD + c] = v;
}

// ---------------- final: MLP head + log_softmax ----------------

__global__ void k_final(const float* __restrict__ hin,
                        const float* __restrict__ w1, const float* __restrict__ mb1,
                        const float* __restrict__ w2, const float* __restrict__ mb2,
                        float* __restrict__ out) {
    __shared__ float sw1[HD * MID], sw2[MID * OUTD], sb1[MID], sb2[OUTD];
    for (int t = threadIdx.x; t < HD * MID; t += blockDim.x) sw1[t] = w1[t];
    for (int t = threadIdx.x; t < MID * OUTD; t += blockDim.x) sw2[t] = w2[t];
    if (threadIdx.x < MID) sb1[threadIdx.x] = mb1[threadIdx.x];
    if (threadIdx.x < OUTD) sb2[threadIdx.x] = mb2[threadIdx.x];
    __syncthreads();
    int n = blockIdx.x * blockDim.x + threadIdx.x;
    if (n >= NN) return;
    float h[HD];
    const float* ar = hin + (size_t)n * HD;
#pragma unroll
    for (int k = 0; k < HD; ++k) h[k] = ar[k];
    float t[MID];
#pragma unroll
    for (int j = 0; j < MID; ++j) {
        float a = sb1[j];
#pragma unroll
        for (int k = 0; k < HD; ++k) a += h[k] * sw1[k * MID + j];
        t[j] = fmaxf(a, 0.f);
    }
    float o[OUTD];
#pragma unroll
    for (int j = 0; j < OUTD; ++j) {
        float a = sb2[j];
#pragma unroll
        for (int k = 0; k < MID; ++k) a += t[k] * sw2[k * OUTD + j];
        o[j] = a;
    }
    float mx = o[0];
#pragma unroll
    for (int j = 1; j < OUTD; ++j) mx = fmaxf(mx, o[j]);
    float se = 0.f;
#pragma unroll
    for (int j = 0; j < OUTD; ++j) se += __expf(o[j] - mx);
    float lse = __logf(se) + mx;
    float* orow = out + (size_t)n * OUTD;
#pragma unroll
    for (int j = 0; j < OUTD; ++j) orow[j] = o[j] - lse;
}

// ---------------- launch ----------------

extern "C" void kernel_launch(void* const* d_in, const int* in_sizes, int n_in,
                              void* d_out, int out_size, void* d_ws, size_t ws_size,
                              hipStream_t stream) {
    const float* x     = (const float*)d_in[0];
    const int*   ei    = (const int*)d_in[1];
    const float* W0    = (const float*)d_in[2];
    const float* b0    = (const float*)d_in[3];
    const float* W1    = (const float*)d_in[4];
    const float* b1    = (const float*)d_in[5];
    const float* W2    = (const float*)d_in[6];
    const float* b2    = (const float*)d_in[7];
    const float* ln0_g = (const float*)d_in[8];
    const float* ln0_b = (const float*)d_in[9];
    const float* ln1_g = (const float*)d_in[10];
    const float* ln1_b = (const float*)d_in[11];
    const float* mp_w1 = (const float*)d_in[12];
    const float* mp_b1 = (const float*)d_in[13];
    const float* mp_w2 = (const float*)d_in[14];
    const float* mp_b2 = (const float*)d_in[15];
    float* out = (float*)d_out;

    const int* src = ei;        // edge_index[0]
    const int* dst = ei + NE;   // edge_index[1]

    char* w = (char*)d_ws;
    auto align256 = [](size_t v) { return (v + 255) & ~(size_t)255; };
    int* g_bincur  = (int*)w;   w += align256((size_t)NB * 4);
    int* g_binexcl = (int*)w;   w += align256((size_t)NB * 4);
    int* row_ptr   = (int*)w;   w += align256((size_t)(NN + 1) * 4);
    float* dis     = (float*)w; w += align256((size_t)NN * 4);
    char* uni = w;              // union region (staging vs activations)
    unsigned int* staged = (unsigned int*)uni;                    // NB*CAP*4 = 16.0 MB
    unsigned short* bufB = (unsigned short*)uni;                  // bf16 hs, 6.4 MB
    float* bufA = (float*)(uni + align256((size_t)NN * HD * 2));  // f32 acts, 12.8 MB
    size_t uni_sz = align256((size_t)NB * CAP * 4);
    size_t uni_sz2 = align256((size_t)NN * HD * 2) + align256((size_t)NN * HD * 4);
    w = uni + (uni_sz > uni_sz2 ? uni_sz : uni_sz2);
    int* csr_src = (int*)w;

    const int BS = 256;
    int gN   = (NN + BS - 1) / BS;          // 391
    int gA   = (NE + EPB - 1) / EPB;        // 391
    int gN32 = (NN * HD + BS - 1) / BS;

    // CSR build (binned counting sort)
    k_zero_bins<<<1, 512, 0, stream>>>(g_bincur);
    k_binA<<<gA, ABS, 0, stream>>>(src, dst, g_bincur, staged);
    k_binscan<<<1, 512, 0, stream>>>(g_bincur, g_binexcl, row_ptr);
    k_binC<<<NB, CBS, 0, stream>>>(g_bincur, g_binexcl, staged, row_ptr, dis, csr_src);

    // layer 0
    k_gemm<DIN><<<gN, BS, 0, stream>>>(x, W0, dis, bufB);
    k_gather<1><<<gN32, BS, 0, stream>>>(row_ptr, csr_src, dis, bufB, b0,
                                         ln0_g, ln0_b, bufA);
    // layer 1
    k_gemm<HD><<<gN, BS, 0, stream>>>(bufA, W1, dis, bufB);
    k_gather<1><<<gN32, BS, 0, stream>>>(row_ptr, csr_src, dis, bufB, b1,
                                         ln1_g, ln1_b, bufA);
    // layer 2 (no LN)
    k_gemm<HD><<<gN, BS, 0, stream>>>(bufA, W2, dis, bufB);
    k_gather<0><<<gN32, BS, 0, stream>>>(row_ptr, csr_src, dis, bufB, b2,
                                         nullptr, nullptr, bufA);

    // head
    k_final<<<gN, BS, 0, stream>>>(bufA, mp_w1, mp_b1, mp_w2, mp_b2, out);
}

// Round 8
// 269.728 us; speedup vs baseline: 1.3028x; 1.1110x over previous
//
#include <hip/hip_runtime.h>

#define NN 100000
#define NE 3200000
#define DIN 128
#define HD 32
#define MID 16
#define OUTD 8
#define LN_EPS 1e-5f

#define BINSHIFT 8                 // 256 nodes per bin
#define NB 391                     // ceil(NN / 256)
#define CAP 10240                  // bin capacity (mean 8192)
#define EPB 8192                   // edges per pass-A block (391 blocks, 21-edge runs)
#define ABS 1024                   // pass-A block size (16 waves/block)
#define AITER (EPB / ABS)          // 8
#define CBS 1024                   // pass-C block size

// ---------------- bf16 helpers ----------------

__device__ __forceinline__ float bf2f(unsigned short u) {
    union { unsigned int i; float f; } c;
    c.i = ((unsigned int)u) << 16;
    return c.f;
}
__device__ __forceinline__ unsigned short f2bf(float f) {
    union { float f; unsigned int i; } c;
    c.f = f;
    unsigned int r = c.i + 0x7FFFu + ((c.i >> 16) & 1u);  // RNE
    return (unsigned short)(r >> 16);
}
__device__ __forceinline__ unsigned int pack2(float a, float b) {
    return (unsigned int)f2bf(a) | ((unsigned int)f2bf(b) << 16);
}
// u = two packed bf16 (channels c, c+1): accumulate into a0, a1
__device__ __forceinline__ void addpk(float& a0, float& a1, unsigned int u) {
    union { unsigned int i; float f; } lo, hi;
    lo.i = u << 16;
    hi.i = u & 0xFFFF0000u;
    a0 += lo.f;
    a1 += hi.f;
}

// ---------------- binned CSR build ----------------

__global__ void k_zero_bins(int* __restrict__ g_bincur) {
    int i = blockIdx.x * blockDim.x + threadIdx.x;
    if (i < NB) g_bincur[i] = 0;
}

__global__ __launch_bounds__(ABS) void k_binA(const int* __restrict__ src,
                                              const int* __restrict__ dst,
                                              int* __restrict__ g_bincur,
                                              unsigned int* __restrict__ staged) {
    __shared__ int cnt[NB];
    __shared__ int base[NB];
    int tid = threadIdx.x;
    for (int t = tid; t < NB; t += ABS) cnt[t] = 0;
    __syncthreads();
    int e0 = blockIdx.x * EPB;
    int dreg[AITER];
#pragma unroll
    for (int i = 0; i < AITER; ++i) {
        int e = e0 + i * ABS + tid;
        dreg[i] = (e < NE) ? dst[e] : -1;
        if (dreg[i] >= 0) atomicAdd(&cnt[dreg[i] >> BINSHIFT], 1);
    }
    __syncthreads();
    for (int t = tid; t < NB; t += ABS) {
        int c = cnt[t];
        base[t] = c ? atomicAdd(&g_bincur[t], c) : 0;
        cnt[t] = 0;  // reuse as intra-block cursor
    }
    __syncthreads();
#pragma unroll
    for (int i = 0; i < AITER; ++i) {
        int e = e0 + i * ABS + tid;
        int d = dreg[i];
        if (d >= 0) {
            int b = d >> BINSHIFT;
            int k = base[b] + atomicAdd(&cnt[b], 1);
            if (k < CAP)
                staged[(size_t)b * CAP + k] =
                    ((unsigned int)(d & 255) << 24) | (unsigned int)src[e];
        }
    }
}

__global__ void k_binscan(const int* __restrict__ g_bincur, int* __restrict__ g_binexcl,
                          int* __restrict__ row_ptr) {
    __shared__ int s[512];
    int v = (threadIdx.x < NB) ? min(g_bincur[threadIdx.x], CAP) : 0;
    s[threadIdx.x] = v;
    __syncthreads();
#pragma unroll
    for (int off = 1; off < 512; off <<= 1) {
        int t = (threadIdx.x >= off) ? s[threadIdx.x - off] : 0;
        __syncthreads();
        s[threadIdx.x] += t;
        __syncthreads();
    }
    if (threadIdx.x < NB) g_binexcl[threadIdx.x] = s[threadIdx.x] - v;
    if (threadIdx.x == NB - 1) row_ptr[NN] = s[threadIdx.x];
}

__global__ __launch_bounds__(CBS) void k_binC(const int* __restrict__ g_bincur,
                                              const int* __restrict__ g_binexcl,
                                              const unsigned int* __restrict__ staged,
                                              int* __restrict__ row_ptr,
                                              float* __restrict__ dis,
                                              int* __restrict__ csr_src) {
    __shared__ int cnt[256];
    __shared__ int scn[256];
    int b = blockIdx.x;
    int tid = threadIdx.x;
    int tot = min(g_bincur[b], CAP);
    if (tid < 256) cnt[tid] = 0;
    __syncthreads();
    const unsigned int* st = staged + (size_t)b * CAP;
    for (int i = tid; i < tot; i += CBS)
        atomicAdd(&cnt[st[i] >> 24], 1);
    __syncthreads();
    int v = 0;
    if (tid < 256) {
        v = cnt[tid];
        scn[tid] = v;
    }
    __syncthreads();
#pragma unroll
    for (int off = 1; off < 256; off <<= 1) {
        int t = (tid < 256 && tid >= off) ? scn[tid - off] : 0;
        __syncthreads();
        if (tid < 256) scn[tid] += t;
        __syncthreads();
    }
    int gbase = g_binexcl[b];
    if (tid < 256) {
        int excl = scn[tid] - v;
        int node = (b << BINSHIFT) + tid;
        if (node < NN) {
            row_ptr[node] = gbase + excl;
            dis[node] = rsqrtf((float)(v + 1));  // +1 self-loop
        }
        cnt[tid] = excl;  // reuse as scatter cursor
    }
    __syncthreads();
    for (int i = tid; i < tot; i += CBS) {
        unsigned int p = st[i];
        int rank = atomicAdd(&cnt[p >> 24], 1);
        csr_src[gbase + rank] = (int)(p & 0xFFFFFFu);
    }
}

// ---------------- GEMM: thread = node, W via uniform (SGPR) loads ----------------
// hs[n][j] = (x[n] @ W)[j] * dis[n]  packed bf16

template <int K>
__global__ void k_gemm(const float* __restrict__ x, const float* __restrict__ W,
                       const float* __restrict__ dis, unsigned short* __restrict__ hs) {
    int n = blockIdx.x * blockDim.x + threadIdx.x;
    if (n >= NN) return;
    float d = dis[n];
    const float* xr = x + (size_t)n * K;
    float acc[HD];
#pragma unroll
    for (int j = 0; j < HD; ++j) acc[j] = 0.f;
    for (int k0 = 0; k0 < K; k0 += 4) {
        float4 xv = *reinterpret_cast<const float4*>(xr + k0);
#pragma unroll
        for (int kk = 0; kk < 4; ++kk) {
            float xk = kk == 0 ? xv.x : kk == 1 ? xv.y : kk == 2 ? xv.z : xv.w;
#pragma unroll
            for (int j = 0; j < HD; ++j)
                acc[j] = fmaf(xk, W[(k0 + kk) * HD + j], acc[j]);  // W uniform -> s_load
        }
    }
    uint4* hv = reinterpret_cast<uint4*>(hs + (size_t)n * HD);
#pragma unroll
    for (int q = 0; q < 4; ++q) {
        uint4 p;
        p.x = pack2(acc[q * 8 + 0] * d, acc[q * 8 + 1] * d);
        p.y = pack2(acc[q * 8 + 2] * d, acc[q * 8 + 3] * d);
        p.z = pack2(acc[q * 8 + 4] * d, acc[q * 8 + 5] * d);
        p.w = pack2(acc[q * 8 + 6] * d, acc[q * 8 + 7] * d);
        hv[q] = p;
    }
}

// ---------------- gather: 8 lanes/node, 4 channels/lane (uint2 = 8B) ----------------
// out = dis[n]*(hs[n] + sum hs[src]) + bias, relu, (LN)

template <int DO_LN>
__global__ void k_gather(const int* __restrict__ row_ptr, const int* __restrict__ csr_src,
                         const float* __restrict__ dis,
                         const unsigned short* __restrict__ h,
                         const float* __restrict__ bias,
                         const float* __restrict__ g, const float* __restrict__ bln,
                         float* __restrict__ out) {
    int idx = blockIdx.x * blockDim.x + threadIdx.x;
    int n = idx >> 3, sub = idx & 7;
    if (n >= NN) return;
    int c0 = sub << 2;  // first of this lane's 4 channels

    // self-loop (hs already scaled by dis[src]=dis[n])
    uint2 u = *reinterpret_cast<const uint2*>(h + (size_t)n * HD + c0);
    float a0 = 0.f, a1 = 0.f, a2 = 0.f, a3 = 0.f;
    addpk(a0, a1, u.x);
    addpk(a2, a3, u.y);

    int e = row_ptr[n], end = row_ptr[n + 1];
    // peel to 16B alignment of csr_src index loads
    while (e < end && (e & 3)) {
        int s = csr_src[e];
        uint2 hv = *reinterpret_cast<const uint2*>(h + (size_t)s * HD + c0);
        addpk(a0, a1, hv.x);
        addpk(a2, a3, hv.y);
        ++e;
    }
    for (; e + 3 < end; e += 4) {
        int4 si = *reinterpret_cast<const int4*>(csr_src + e);  // broadcast in group
        uint2 h0 = *reinterpret_cast<const uint2*>(h + (size_t)si.x * HD + c0);
        uint2 h1 = *reinterpret_cast<const uint2*>(h + (size_t)si.y * HD + c0);
        uint2 h2 = *reinterpret_cast<const uint2*>(h + (size_t)si.z * HD + c0);
        uint2 h3 = *reinterpret_cast<const uint2*>(h + (size_t)si.w * HD + c0);
        addpk(a0, a1, h0.x); addpk(a2, a3, h0.y);
        addpk(a0, a1, h1.x); addpk(a2, a3, h1.y);
        addpk(a0, a1, h2.x); addpk(a2, a3, h2.y);
        addpk(a0, a1, h3.x); addpk(a2, a3, h3.y);
    }
    for (; e < end; ++e) {
        int s = csr_src[e];
        uint2 hv = *reinterpret_cast<const uint2*>(h + (size_t)s * HD + c0);
        addpk(a0, a1, hv.x);
        addpk(a2, a3, hv.y);
    }

    float d = dis[n];
    float4 bv = *reinterpret_cast<const float4*>(bias + c0);
    float v0 = fmaxf(fmaf(a0, d, bv.x), 0.f);
    float v1 = fmaxf(fmaf(a1, d, bv.y), 0.f);
    float v2 = fmaxf(fmaf(a2, d, bv.z), 0.f);
    float v3 = fmaxf(fmaf(a3, d, bv.w), 0.f);

    if (DO_LN) {
        float s = (v0 + v1) + (v2 + v3);
        float s2 = (v0 * v0 + v1 * v1) + (v2 * v2 + v3 * v3);
#pragma unroll
        for (int m = 4; m >= 1; m >>= 1) {
            s += __shfl_xor(s, m, 8);
            s2 += __shfl_xor(s2, m, 8);
        }
        float mean = s * (1.f / 32.f);
        float var = s2 * (1.f / 32.f) - mean * mean;
        float r = rsqrtf(var + LN_EPS);
        float4 gv = *reinterpret_cast<const float4*>(g + c0);
        float4 lb = *reinterpret_cast<const float4*>(bln + c0);
        v0 = (v0 - mean) * r * gv.x + lb.x;
        v1 = (v1 - mean) * r * gv.y + lb.y;
        v2 = (v2 - mean) * r * gv.z + lb.z;
        v3 = (v3 - mean) * r * gv.w + lb.w;
    }
    *reinterpret_cast<float4*>(out + (size_t)n * HD + c0) = make_float4(v0, v1, v2, v3);
}

// ---------------- final: MLP head + log_softmax ----------------

__global__ void k_final(const float* __restrict__ hin,
                        const float* __restrict__ w1, const float* __restrict__ mb1,
                        const float* __restrict__ w2, const float* __restrict__ mb2,
                        float* __restrict__ out) {
    __shared__ float sw1[HD * MID], sw2[MID * OUTD], sb1[MID], sb2[OUTD];
    for (int t = threadIdx.x; t < HD * MID; t += blockDim.x) sw1[t] = w1[t];
    for (int t = threadIdx.x; t < MID * OUTD; t += blockDim.x) sw2[t] = w2[t];
    if (threadIdx.x < MID) sb1[threadIdx.x] = mb1[threadIdx.x];
    if (threadIdx.x < OUTD) sb2[threadIdx.x] = mb2[threadIdx.x];
    __syncthreads();
    int n = blockIdx.x * blockDim.x + threadIdx.x;
    if (n >= NN) return;
    float h[HD];
    const float* ar = hin + (size_t)n * HD;
#pragma unroll
    for (int k = 0; k < HD; ++k) h[k] = ar[k];
    float t[MID];
#pragma unroll
    for (int j = 0; j < MID; ++j) {
        float a = sb1[j];
#pragma unroll
        for (int k = 0; k < HD; ++k) a += h[k] * sw1[k * MID + j];
        t[j] = fmaxf(a, 0.f);
    }
    float o[OUTD];
#pragma unroll
    for (int j = 0; j < OUTD; ++j) {
        float a = sb2[j];
#pragma unroll
        for (int k = 0; k < MID; ++k) a += t[k] * sw2[k * OUTD + j];
        o[j] = a;
    }
    float mx = o[0];
#pragma unroll
    for (int j = 1; j < OUTD; ++j) mx = fmaxf(mx, o[j]);
    float se = 0.f;
#pragma unroll
    for (int j = 0; j < OUTD; ++j) se += __expf(o[j] - mx);
    float lse = __logf(se) + mx;
    float* orow = out + (size_t)n * OUTD;
#pragma unroll
    for (int j = 0; j < OUTD; ++j) orow[j] = o[j] - lse;
}

// ---------------- launch ----------------

extern "C" void kernel_launch(void* const* d_in, const int* in_sizes, int n_in,
                              void* d_out, int out_size, void* d_ws, size_t ws_size,
                              hipStream_t stream) {
    const float* x     = (const float*)d_in[0];
    const int*   ei    = (const int*)d_in[1];
    const float* W0    = (const float*)d_in[2];
    const float* b0    = (const float*)d_in[3];
    const float* W1    = (const float*)d_in[4];
    const float* b1    = (const float*)d_in[5];
    const float* W2    = (const float*)d_in[6];
    const float* b2    = (const float*)d_in[7];
    const float* ln0_g = (const float*)d_in[8];
    const float* ln0_b = (const float*)d_in[9];
    const float* ln1_g = (const float*)d_in[10];
    const float* ln1_b = (const float*)d_in[11];
    const float* mp_w1 = (const float*)d_in[12];
    const float* mp_b1 = (const float*)d_in[13];
    const float* mp_w2 = (const float*)d_in[14];
    const float* mp_b2 = (const float*)d_in[15];
    float* out = (float*)d_out;

    const int* src = ei;        // edge_index[0]
    const int* dst = ei + NE;   // edge_index[1]

    char* w = (char*)d_ws;
    auto align256 = [](size_t v) { return (v + 255) & ~(size_t)255; };
    int* g_bincur  = (int*)w;   w += align256((size_t)NB * 4);
    int* g_binexcl = (int*)w;   w += align256((size_t)NB * 4);
    int* row_ptr   = (int*)w;   w += align256((size_t)(NN + 1) * 4);
    float* dis     = (float*)w; w += align256((size_t)NN * 4);
    char* uni = w;              // union region (staging vs activations)
    unsigned int* staged = (unsigned int*)uni;                    // NB*CAP*4 = 16.0 MB
    unsigned short* bufB = (unsigned short*)uni;                  // bf16 hs, 6.4 MB
    float* bufA = (float*)(uni + align256((size_t)NN * HD * 2));  // f32 acts, 12.8 MB
    size_t uni_sz = align256((size_t)NB * CAP * 4);
    size_t uni_sz2 = align256((size_t)NN * HD * 2) + align256((size_t)NN * HD * 4);
    w = uni + (uni_sz > uni_sz2 ? uni_sz : uni_sz2);
    int* csr_src = (int*)w;

    const int BS = 256;
    int gN  = (NN + BS - 1) / BS;           // 391
    int gA  = (NE + EPB - 1) / EPB;         // 391
    int gN8 = (NN * 8 + BS - 1) / BS;       // 3125

    // CSR build (binned counting sort)
    k_zero_bins<<<1, 512, 0, stream>>>(g_bincur);
    k_binA<<<gA, ABS, 0, stream>>>(src, dst, g_bincur, staged);
    k_binscan<<<1, 512, 0, stream>>>(g_bincur, g_binexcl, row_ptr);
    k_binC<<<NB, CBS, 0, stream>>>(g_bincur, g_binexcl, staged, row_ptr, dis, csr_src);

    // layer 0
    k_gemm<DIN><<<gN, BS, 0, stream>>>(x, W0, dis, bufB);
    k_gather<1><<<gN8, BS, 0, stream>>>(row_ptr, csr_src, dis, bufB, b0,
                                        ln0_g, ln0_b, bufA);
    // layer 1
    k_gemm<HD><<<gN, BS, 0, stream>>>(bufA, W1, dis, bufB);
    k_gather<1><<<gN8, BS, 0, stream>>>(row_ptr, csr_src, dis, bufB, b1,
                                        ln1_g, ln1_b, bufA);
    // layer 2 (no LN)
    k_gemm<HD><<<gN, BS, 0, stream>>>(bufA, W2, dis, bufB);
    k_gather<0><<<gN8, BS, 0, stream>>>(row_ptr, csr_src, dis, bufB, b2,
                                        nullptr, nullptr, bufA);

    // head
    k_final<<<gN, BS, 0, stream>>>(bufA, mp_w1, mp_b1, mp_w2, mp_b2, out);
}

// Round 9
// 261.200 us; speedup vs baseline: 1.3453x; 1.0327x over previous
//
#include <hip/hip_runtime.h>

#define NN 100000
#define NE 3200000
#define DIN 128
#define HD 32
#define MID 16
#define OUTD 8
#define LN_EPS 1e-5f

#define BINSHIFT 8                 // 256 nodes per bin
#define NB 391                     // ceil(NN / 256)
#define CAP 10240                  // bin capacity (mean 8192)
#define EPB 8192                   // edges per pass-A block (391 blocks, 21-edge runs)
#define ABS 1024                   // pass-A block size (16 waves/block)
#define AITER (EPB / ABS)          // 8
#define CBS 1024                   // pass-C block size

// ---------------- bf16 helpers ----------------

__device__ __forceinline__ float bf2f(unsigned short u) {
    union { unsigned int i; float f; } c;
    c.i = ((unsigned int)u) << 16;
    return c.f;
}
__device__ __forceinline__ unsigned short f2bf(float f) {
    union { float f; unsigned int i; } c;
    c.f = f;
    unsigned int r = c.i + 0x7FFFu + ((c.i >> 16) & 1u);  // RNE
    return (unsigned short)(r >> 16);
}
__device__ __forceinline__ unsigned int pack2(float a, float b) {
    return (unsigned int)f2bf(a) | ((unsigned int)f2bf(b) << 16);
}
// u = two packed bf16 (channels c, c+1): accumulate into a0, a1
__device__ __forceinline__ void addpk(float& a0, float& a1, unsigned int u) {
    union { unsigned int i; float f; } lo, hi;
    lo.i = u << 16;
    hi.i = u & 0xFFFF0000u;
    a0 += lo.f;
    a1 += hi.f;
}

// ---------------- binned CSR build ----------------

__global__ void k_zero_bins(int* __restrict__ g_bincur) {
    int i = blockIdx.x * blockDim.x + threadIdx.x;
    if (i < NB) g_bincur[i] = 0;
}

__global__ __launch_bounds__(ABS) void k_binA(const int* __restrict__ src,
                                              const int* __restrict__ dst,
                                              int* __restrict__ g_bincur,
                                              unsigned int* __restrict__ staged) {
    __shared__ int cnt[NB];
    __shared__ int base[NB];
    int tid = threadIdx.x;
    for (int t = tid; t < NB; t += ABS) cnt[t] = 0;
    __syncthreads();
    int e0 = blockIdx.x * EPB;
    int dreg[AITER];
#pragma unroll
    for (int i = 0; i < AITER; ++i) {
        int e = e0 + i * ABS + tid;
        dreg[i] = (e < NE) ? dst[e] : -1;
        if (dreg[i] >= 0) atomicAdd(&cnt[dreg[i] >> BINSHIFT], 1);
    }
    __syncthreads();
    for (int t = tid; t < NB; t += ABS) {
        int c = cnt[t];
        base[t] = c ? atomicAdd(&g_bincur[t], c) : 0;
        cnt[t] = 0;  // reuse as intra-block cursor
    }
    __syncthreads();
#pragma unroll
    for (int i = 0; i < AITER; ++i) {
        int e = e0 + i * ABS + tid;
        int d = dreg[i];
        if (d >= 0) {
            int b = d >> BINSHIFT;
            int k = base[b] + atomicAdd(&cnt[b], 1);
            if (k < CAP)
                staged[(size_t)b * CAP + k] =
                    ((unsigned int)(d & 255) << 24) | (unsigned int)src[e];
        }
    }
}

__global__ void k_binscan(const int* __restrict__ g_bincur, int* __restrict__ g_binexcl,
                          int* __restrict__ row_ptr) {
    __shared__ int s[512];
    int v = (threadIdx.x < NB) ? min(g_bincur[threadIdx.x], CAP) : 0;
    s[threadIdx.x] = v;
    __syncthreads();
#pragma unroll
    for (int off = 1; off < 512; off <<= 1) {
        int t = (threadIdx.x >= off) ? s[threadIdx.x - off] : 0;
        __syncthreads();
        s[threadIdx.x] += t;
        __syncthreads();
    }
    if (threadIdx.x < NB) g_binexcl[threadIdx.x] = s[threadIdx.x] - v;
    if (threadIdx.x == NB - 1) row_ptr[NN] = s[threadIdx.x];
}

__global__ __launch_bounds__(CBS) void k_binC(const int* __restrict__ g_bincur,
                                              const int* __restrict__ g_binexcl,
                                              const unsigned int* __restrict__ staged,
                                              int* __restrict__ row_ptr,
                                              float* __restrict__ dis,
                                              int* __restrict__ csr_src) {
    __shared__ int cnt[256];
    __shared__ int scn[256];
    int b = blockIdx.x;
    int tid = threadIdx.x;
    int tot = min(g_bincur[b], CAP);
    if (tid < 256) cnt[tid] = 0;
    __syncthreads();
    const unsigned int* st = staged + (size_t)b * CAP;
    for (int i = tid; i < tot; i += CBS)
        atomicAdd(&cnt[st[i] >> 24], 1);
    __syncthreads();
    int v = 0;
    if (tid < 256) {
        v = cnt[tid];
        scn[tid] = v;
    }
    __syncthreads();
#pragma unroll
    for (int off = 1; off < 256; off <<= 1) {
        int t = (tid < 256 && tid >= off) ? scn[tid - off] : 0;
        __syncthreads();
        if (tid < 256) scn[tid] += t;
        __syncthreads();
    }
    int gbase = g_binexcl[b];
    if (tid < 256) {
        int excl = scn[tid] - v;
        int node = (b << BINSHIFT) + tid;
        if (node < NN) {
            row_ptr[node] = gbase + excl;
            dis[node] = rsqrtf((float)(v + 1));  // +1 self-loop
        }
        cnt[tid] = excl;  // reuse as scatter cursor
    }
    __syncthreads();
    for (int i = tid; i < tot; i += CBS) {
        unsigned int p = st[i];
        int rank = atomicAdd(&cnt[p >> 24], 1);
        csr_src[gbase + rank] = (int)(p & 0xFFFFFFu);
    }
}

// ---------------- GEMM: block = 64 nodes x 4 waves; wave = 8-output group ----------------
// hs[n][j] = (x[n] @ W)[j] * dis[n]  packed bf16

template <int K>
__global__ __launch_bounds__(256) void k_gemm(const float* __restrict__ x,
                                              const float* __restrict__ W,
                                              const float* __restrict__ dis,
                                              unsigned short* __restrict__ hs) {
    int lane = threadIdx.x & 63;
    int q = __builtin_amdgcn_readfirstlane(threadIdx.x >> 6);  // 0..3, SGPR
    int n = blockIdx.x * 64 + lane;
    if (n >= NN) return;
    const float* xr = x + (size_t)n * K;
    const float* Wq = W + q * 8;  // scalar base
    float acc[8];
#pragma unroll
    for (int j = 0; j < 8; ++j) acc[j] = 0.f;
    for (int k0 = 0; k0 < K; k0 += 4) {
        float4 xv = *reinterpret_cast<const float4*>(xr + k0);
#pragma unroll
        for (int kk = 0; kk < 4; ++kk) {
            float xk = kk == 0 ? xv.x : kk == 1 ? xv.y : kk == 2 ? xv.z : xv.w;
#pragma unroll
            for (int j = 0; j < 8; ++j)
                acc[j] = fmaf(xk, Wq[(k0 + kk) * HD + j], acc[j]);  // uniform -> s_load
        }
    }
    float d = dis[n];
    uint4 p;
    p.x = pack2(acc[0] * d, acc[1] * d);
    p.y = pack2(acc[2] * d, acc[3] * d);
    p.z = pack2(acc[4] * d, acc[5] * d);
    p.w = pack2(acc[6] * d, acc[7] * d);
    *reinterpret_cast<uint4*>(hs + (size_t)n * HD + q * 8) = p;
}

// ---------------- gather: 8 lanes/node, 4 channels/lane (uint2 = 8B) ----------------
// out = dis[n]*(hs[n] + sum hs[src]) + bias, relu, (LN)

template <int DO_LN>
__global__ void k_gather(const int* __restrict__ row_ptr, const int* __restrict__ csr_src,
                         const float* __restrict__ dis,
                         const unsigned short* __restrict__ h,
                         const float* __restrict__ bias,
                         const float* __restrict__ g, const float* __restrict__ bln,
                         float* __restrict__ out) {
    int idx = blockIdx.x * blockDim.x + threadIdx.x;
    int n = idx >> 3, sub = idx & 7;
    if (n >= NN) return;
    int c0 = sub << 2;  // first of this lane's 4 channels

    // self-loop (hs already scaled by dis[src]=dis[n])
    uint2 u = *reinterpret_cast<const uint2*>(h + (size_t)n * HD + c0);
    float a0 = 0.f, a1 = 0.f, a2 = 0.f, a3 = 0.f;
    addpk(a0, a1, u.x);
    addpk(a2, a3, u.y);

    int e = row_ptr[n], end = row_ptr[n + 1];
    // peel to 16B alignment of csr_src index loads
    while (e < end && (e & 3)) {
        int s = csr_src[e];
        uint2 hv = *reinterpret_cast<const uint2*>(h + (size_t)s * HD + c0);
        addpk(a0, a1, hv.x);
        addpk(a2, a3, hv.y);
        ++e;
    }
    for (; e + 3 < end; e += 4) {
        int4 si = *reinterpret_cast<const int4*>(csr_src + e);  // broadcast in group
        uint2 h0 = *reinterpret_cast<const uint2*>(h + (size_t)si.x * HD + c0);
        uint2 h1 = *reinterpret_cast<const uint2*>(h + (size_t)si.y * HD + c0);
        uint2 h2 = *reinterpret_cast<const uint2*>(h + (size_t)si.z * HD + c0);
        uint2 h3 = *reinterpret_cast<const uint2*>(h + (size_t)si.w * HD + c0);
        addpk(a0, a1, h0.x); addpk(a2, a3, h0.y);
        addpk(a0, a1, h1.x); addpk(a2, a3, h1.y);
        addpk(a0, a1, h2.x); addpk(a2, a3, h2.y);
        addpk(a0, a1, h3.x); addpk(a2, a3, h3.y);
    }
    for (; e < end; ++e) {
        int s = csr_src[e];
        uint2 hv = *reinterpret_cast<const uint2*>(h + (size_t)s * HD + c0);
        addpk(a0, a1, hv.x);
        addpk(a2, a3, hv.y);
    }

    float d = dis[n];
    float4 bv = *reinterpret_cast<const float4*>(bias + c0);
    float v0 = fmaxf(fmaf(a0, d, bv.x), 0.f);
    float v1 = fmaxf(fmaf(a1, d, bv.y), 0.f);
    float v2 = fmaxf(fmaf(a2, d, bv.z), 0.f);
    float v3 = fmaxf(fmaf(a3, d, bv.w), 0.f);

    if (DO_LN) {
        float s = (v0 + v1) + (v2 + v3);
        float s2 = (v0 * v0 + v1 * v1) + (v2 * v2 + v3 * v3);
#pragma unroll
        for (int m = 4; m >= 1; m >>= 1) {
            s += __shfl_xor(s, m, 8);
            s2 += __shfl_xor(s2, m, 8);
        }
        float mean = s * (1.f / 32.f);
        float var = s2 * (1.f / 32.f) - mean * mean;
        float r = rsqrtf(var + LN_EPS);
        float4 gv = *reinterpret_cast<const float4*>(g + c0);
        float4 lb = *reinterpret_cast<const float4*>(bln + c0);
        v0 = (v0 - mean) * r * gv.x + lb.x;
        v1 = (v1 - mean) * r * gv.y + lb.y;
        v2 = (v2 - mean) * r * gv.z + lb.z;
        v3 = (v3 - mean) * r * gv.w + lb.w;
    }
    *reinterpret_cast<float4*>(out + (size_t)n * HD + c0) = make_float4(v0, v1, v2, v3);
}

// ---------------- final: MLP head + log_softmax ----------------

__global__ void k_final(const float* __restrict__ hin,
                        const float* __restrict__ w1, const float* __restrict__ mb1,
                        const float* __restrict__ w2, const float* __restrict__ mb2,
                        float* __restrict__ out) {
    __shared__ float sw1[HD * MID], sw2[MID * OUTD], sb1[MID], sb2[OUTD];
    for (int t = threadIdx.x; t < HD * MID; t += blockDim.x) sw1[t] = w1[t];
    for (int t = threadIdx.x; t < MID * OUTD; t += blockDim.x) sw2[t] = w2[t];
    if (threadIdx.x < MID) sb1[threadIdx.x] = mb1[threadIdx.x];
    if (threadIdx.x < OUTD) sb2[threadIdx.x] = mb2[threadIdx.x];
    __syncthreads();
    int n = blockIdx.x * blockDim.x + threadIdx.x;
    if (n >= NN) return;
    float h[HD];
    const float* ar = hin + (size_t)n * HD;
#pragma unroll
    for (int k = 0; k < HD; ++k) h[k] = ar[k];
    float t[MID];
#pragma unroll
    for (int j = 0; j < MID; ++j) {
        float a = sb1[j];
#pragma unroll
        for (int k = 0; k < HD; ++k) a += h[k] * sw1[k * MID + j];
        t[j] = fmaxf(a, 0.f);
    }
    float o[OUTD];
#pragma unroll
    for (int j = 0; j < OUTD; ++j) {
        float a = sb2[j];
#pragma unroll
        for (int k = 0; k < MID; ++k) a += t[k] * sw2[k * OUTD + j];
        o[j] = a;
    }
    float mx = o[0];
#pragma unroll
    for (int j = 1; j < OUTD; ++j) mx = fmaxf(mx, o[j]);
    float se = 0.f;
#pragma unroll
    for (int j = 0; j < OUTD; ++j) se += __expf(o[j] - mx);
    float lse = __logf(se) + mx;
    float* orow = out + (size_t)n * OUTD;
#pragma unroll
    for (int j = 0; j < OUTD; ++j) orow[j] = o[j] - lse;
}

// ---------------- launch ----------------

extern "C" void kernel_launch(void* const* d_in, const int* in_sizes, int n_in,
                              void* d_out, int out_size, void* d_ws, size_t ws_size,
                              hipStream_t stream) {
    const float* x     = (const float*)d_in[0];
    const int*   ei    = (const int*)d_in[1];
    const float* W0    = (const float*)d_in[2];
    const float* b0    = (const float*)d_in[3];
    const float* W1    = (const float*)d_in[4];
    const float* b1    = (const float*)d_in[5];
    const float* W2    = (const float*)d_in[6];
    const float* b2    = (const float*)d_in[7];
    const float* ln0_g = (const float*)d_in[8];
    const float* ln0_b = (const float*)d_in[9];
    const float* ln1_g = (const float*)d_in[10];
    const float* ln1_b = (const float*)d_in[11];
    const float* mp_w1 = (const float*)d_in[12];
    const float* mp_b1 = (const float*)d_in[13];
    const float* mp_w2 = (const float*)d_in[14];
    const float* mp_b2 = (const float*)d_in[15];
    float* out = (float*)d_out;

    const int* src = ei;        // edge_index[0]
    const int* dst = ei + NE;   // edge_index[1]

    char* w = (char*)d_ws;
    auto align256 = [](size_t v) { return (v + 255) & ~(size_t)255; };
    int* g_bincur  = (int*)w;   w += align256((size_t)NB * 4);
    int* g_binexcl = (int*)w;   w += align256((size_t)NB * 4);
    int* row_ptr   = (int*)w;   w += align256((size_t)(NN + 1) * 4);
    float* dis     = (float*)w; w += align256((size_t)NN * 4);
    char* uni = w;              // union region (staging vs activations)
    unsigned int* staged = (unsigned int*)uni;                    // NB*CAP*4 = 16.0 MB
    unsigned short* bufB = (unsigned short*)uni;                  // bf16 hs, 6.4 MB
    float* bufA = (float*)(uni + align256((size_t)NN * HD * 2));  // f32 acts, 12.8 MB
    size_t uni_sz = align256((size_t)NB * CAP * 4);
    size_t uni_sz2 = align256((size_t)NN * HD * 2) + align256((size_t)NN * HD * 4);
    w = uni + (uni_sz > uni_sz2 ? uni_sz : uni_sz2);
    int* csr_src = (int*)w;

    const int BS = 256;
    int gN  = (NN + BS - 1) / BS;           // 391
    int gA  = (NE + EPB - 1) / EPB;         // 391
    int gN8 = (NN * 8 + BS - 1) / BS;       // 3125
    int gG  = (NN + 63) / 64;               // 1563 (gemm: 64 nodes/block)

    // CSR build (binned counting sort)
    k_zero_bins<<<1, 512, 0, stream>>>(g_bincur);
    k_binA<<<gA, ABS, 0, stream>>>(src, dst, g_bincur, staged);
    k_binscan<<<1, 512, 0, stream>>>(g_bincur, g_binexcl, row_ptr);
    k_binC<<<NB, CBS, 0, stream>>>(g_bincur, g_binexcl, staged, row_ptr, dis, csr_src);

    // layer 0
    k_gemm<DIN><<<gG, BS, 0, stream>>>(x, W0, dis, bufB);
    k_gather<1><<<gN8, BS, 0, stream>>>(row_ptr, csr_src, dis, bufB, b0,
                                        ln0_g, ln0_b, bufA);
    // layer 1
    k_gemm<HD><<<gG, BS, 0, stream>>>(bufA, W1, dis, bufB);
    k_gather<1><<<gN8, BS, 0, stream>>>(row_ptr, csr_src, dis, bufB, b1,
                                        ln1_g, ln1_b, bufA);
    // layer 2 (no LN)
    k_gemm<HD><<<gG, BS, 0, stream>>>(bufA, W2, dis, bufB);
    k_gather<0><<<gN8, BS, 0, stream>>>(row_ptr, csr_src, dis, bufB, b2,
                                        nullptr, nullptr, bufA);

    // head
    k_final<<<gN, BS, 0, stream>>>(bufA, mp_w1, mp_b1, mp_w2, mp_b2, out);
}